// Round 3
// baseline (324.208 us; speedup 1.0000x reference)
//
#include <hip/hip_runtime.h>

constexpr int kB  = 16;
constexpr int kM  = 512;
constexpr int kS  = 32;
constexpr int kE  = 128;
constexpr int kV  = 32000;
constexpr int kVN = kV - 1;   // nil (zero) row index
constexpr int kMS = 132;      // padded LDS stride for mem tile (conflict-opt)

// -------------------------------------------------------------------------
// Kernel 1: story embeddings, XCD-sliced.
// combo = bid & 15 : tb = combo>>3 (0: st_bias->memory, 1: out_bias->output),
// ch = combo & 7  -> e-range [ch*16, ch*16+16) = one 64B line per table row.
// Since XCD = bid % 8 (round-robin), each XCD only touches chunk ch of both
// tables: 2 x 2.05 MB of lines -> L2-resident gather working set.
// Block: 256 threads = 16 rows x 16 lanes; each lane owns one e.
// enc[s][e] = 1 + (e-63)(s-15)/1024 (exact f32 match of numpy formula).
// -------------------------------------------------------------------------
__global__ __launch_bounds__(256) void embed_kernel(
    const int*   __restrict__ stories,   // [B*M, S]
    const float* __restrict__ st_bias,   // [VN, E]
    const float* __restrict__ out_bias,  // [VN, E]
    const float* __restrict__ mem_bias,  // [M, E]
    float*       __restrict__ memory,    // [B*M, E]
    float*       __restrict__ output)    // [B*M, E]
{
    __shared__ int sidx[16 * kS];
    const int t     = threadIdx.x;
    const int bid   = blockIdx.x;
    const int combo = bid & 15;
    const int rg    = bid >> 4;          // 512 row-groups of 16 rows
    const int tb    = combo >> 3;
    const int ch    = combo & 7;

    const int row0 = rg * 16;
    sidx[t]       = stories[row0 * kS + t];
    sidx[t + 256] = stories[row0 * kS + 256 + t];
    __syncthreads();

    const int r   = t >> 4;              // row in group
    const int l   = t & 15;
    const int e   = ch * 16 + l;
    const int row = row0 + r;
    const float ef = (float)(e - 63) * (1.0f / 1024.0f);
    const float* tab = tb ? out_bias : st_bias;
    const int* si = sidx + r * kS;

    float a0 = 0.f, a1 = 0.f, a2 = 0.f, a3 = 0.f;
    #pragma unroll
    for (int s = 0; s < kS; s += 4) {
        const int i0 = si[s], i1 = si[s + 1], i2 = si[s + 2], i3 = si[s + 3];
        if (i0 < kVN) a0 = fmaf(tab[(size_t)i0 * kE + e], fmaf(ef, (float)(s     - 15), 1.f), a0);
        if (i1 < kVN) a1 = fmaf(tab[(size_t)i1 * kE + e], fmaf(ef, (float)(s + 1 - 15), 1.f), a1);
        if (i2 < kVN) a2 = fmaf(tab[(size_t)i2 * kE + e], fmaf(ef, (float)(s + 2 - 15), 1.f), a2);
        if (i3 < kVN) a3 = fmaf(tab[(size_t)i3 * kE + e], fmaf(ef, (float)(s + 3 - 15), 1.f), a3);
    }
    float acc = (a0 + a1) + (a2 + a3);
    if (tb == 0) {
        acc += mem_bias[(row & (kM - 1)) * kE + e];
        memory[(size_t)row * kE + e] = acc;
    } else {
        output[(size_t)row * kE + e] = acc;
    }
}

// -------------------------------------------------------------------------
// 4-block barrier (blocks of one b-group), monotonic counter protocol.
// Co-residency guaranteed by cooperative launch. Standard CG-style:
// release-add by thread 0, acquire-spin, syncthreads, trailing fence.
// -------------------------------------------------------------------------
__device__ __forceinline__ void group_barrier(unsigned* ctr, unsigned target)
{
    __syncthreads();                      // all prior LDS/VMEM ops of block done
    if (threadIdx.x == 0) {
        __threadfence();                  // device-scope release of our writes
        __hip_atomic_fetch_add(ctr, 1u, __ATOMIC_ACQ_REL, __HIP_MEMORY_SCOPE_AGENT);
        while (__hip_atomic_load(ctr, __ATOMIC_ACQUIRE, __HIP_MEMORY_SCOPE_AGENT) < target)
            __builtin_amdgcn_s_sleep(8);
    }
    __syncthreads();
    __threadfence();                      // invalidate stale cached lines
}

// -------------------------------------------------------------------------
// Kernel 2 (cooperative, 64 blocks x 1024 threads): q-embed + 3 hops.
// Block (b = bid>>2, qtr = bid&3) holds rows [qtr*128, qtr*128+128) of
// memory[b] (padded stride 132) and output[b] in LDS (~134 KB). Per hop:
//   A: scores for own 128 rows (LDS)        -> scores_g[b][...]  | barrier
//   B: softmax over 512 (redundant) + layer_out partial -> lo_part | barrier
//   C: xb = q + sum(partials); q' = xb @ w   (redundant, local)
// qtr==0 publishes x transposed: xg_t[e*16+b] = relu(q[e]).
// -------------------------------------------------------------------------
__global__ __launch_bounds__(1024) void hops_kernel(
    const int*   __restrict__ queries,   // [B,S]
    const float* __restrict__ q_bias,    // [VN,E]
    const float* __restrict__ memory,    // [B,M,E]
    const float* __restrict__ output,    // [B,M,E]
    const float* __restrict__ w_int,     // [E,E]
    const float* __restrict__ w_out,     // [E,E]
    float*       __restrict__ scores_g,  // [B,M]
    float*       __restrict__ lo_part,   // [B,4,E]
    float*       __restrict__ xg_t,      // [E,B] transposed
    unsigned*    __restrict__ bar)       // [B] counters (pre-zeroed)
{
    __shared__ __align__(16) float mem_lds[128 * kMS];  // 67584 B
    __shared__ __align__(16) float out_lds[128 * kE];   // 65536 B
    __shared__ float sc_all[kM];
    __shared__ __align__(16) float q_s[kE];
    __shared__ float xb[kE];
    __shared__ __align__(16) float part8[8][kE];
    __shared__ float red[16];
    __shared__ int qidx[kS];

    const int bid = blockIdx.x;
    const int b   = bid >> 2;
    const int qtr = bid & 3;
    const int t   = threadIdx.x;
    unsigned* ctr = bar + b;

    // ---- stage quarter into LDS (coalesced float4) ----
    const float* memb = memory + ((size_t)b * kM + qtr * 128) * kE;
    const float* outb = output + ((size_t)b * kM + qtr * 128) * kE;
    #pragma unroll
    for (int i = 0; i < 4; ++i) {
        const int flat = t + i * 1024;        // 0..4095 float4 units
        const int rr = flat >> 5, ff = (flat & 31) * 4;
        *(float4*)&mem_lds[rr * kMS + ff] = *(const float4*)&memb[(size_t)rr * kE + ff];
        *(float4*)&out_lds[rr * kE  + ff] = *(const float4*)&outb[(size_t)rr * kE + ff];
    }
    if (t < kS) qidx[t] = queries[b * kS + t];
    __syncthreads();

    // ---- q embedding (threads 0..255, 8 s-phases x 32 lanes float4) ----
    if (t < 256) {
        const int g = t >> 5, lane = t & 31, e0 = lane * 4;
        const float f0 = (float)(e0 - 63) * (1.0f / 1024.0f);
        const float f1 = (float)(e0 - 62) * (1.0f / 1024.0f);
        const float f2 = (float)(e0 - 61) * (1.0f / 1024.0f);
        const float f3 = (float)(e0 - 60) * (1.0f / 1024.0f);
        float4 a = {0.f, 0.f, 0.f, 0.f};
        #pragma unroll
        for (int j = 0; j < 4; ++j) {
            const int s   = g * 4 + j;
            const int idx = qidx[s];
            const float sf = (float)(s - 15);
            if (idx < kVN) {
                const float4 v = *(const float4*)&q_bias[(size_t)idx * kE + e0];
                a.x = fmaf(v.x, fmaf(f0, sf, 1.f), a.x);
                a.y = fmaf(v.y, fmaf(f1, sf, 1.f), a.y);
                a.z = fmaf(v.z, fmaf(f2, sf, 1.f), a.z);
                a.w = fmaf(v.w, fmaf(f3, sf, 1.f), a.w);
            }
        }
        *(float4*)&part8[g][e0] = a;
    }
    __syncthreads();
    if (t < kE) {
        float s = 0.f;
        #pragma unroll
        for (int g = 0; g < 8; ++g) s += part8[g][t];
        q_s[t] = s;
    }
    __syncthreads();

    unsigned barno = 0;
    for (int hop = 0; hop < 3; ++hop) {
        // ---- A: scores for our 128 rows; 8 lanes per row ----
        {
            const int rw = t >> 3, sub = t & 7;
            const float4* qv = (const float4*)&q_s[sub * 16];
            const float4* mv = (const float4*)&mem_lds[rw * kMS + sub * 16];
            float d = 0.f;
            #pragma unroll
            for (int i = 0; i < 4; ++i) {
                const float4 m4 = mv[i], q4 = qv[i];
                d = fmaf(m4.x, q4.x, d); d = fmaf(m4.y, q4.y, d);
                d = fmaf(m4.z, q4.z, d); d = fmaf(m4.w, q4.w, d);
            }
            d += __shfl_down(d, 4);
            d += __shfl_down(d, 2);
            d += __shfl_down(d, 1);
            if (sub == 0) scores_g[b * kM + qtr * 128 + rw] = d;
        }
        group_barrier(ctr, 4 * (++barno));

        // ---- B: softmax over 512 (redundant per block) ----
        const int wv_id = t >> 6, ln = t & 63;
        const float sv = (t < kM) ? scores_g[b * kM + t] : -1e30f;
        float mr = sv;
        #pragma unroll
        for (int off = 32; off; off >>= 1) mr = fmaxf(mr, __shfl_down(mr, off));
        if (ln == 0) red[wv_id] = mr;
        __syncthreads();
        float mx = red[0];
        #pragma unroll
        for (int i = 1; i < 8; ++i) mx = fmaxf(mx, red[i]);
        const float ex = (t < kM) ? __expf(sv - mx) : 0.f;
        float sr = ex;
        #pragma unroll
        for (int off = 32; off; off >>= 1) sr += __shfl_down(sr, off);
        __syncthreads();
        if (ln == 0) red[wv_id] = sr;
        __syncthreads();
        float tot = 0.f;
        #pragma unroll
        for (int i = 0; i < 8; ++i) tot += red[i];
        const float inv = 1.0f / tot;
        if (t < kM) sc_all[t] = ex * inv;
        __syncthreads();

        // ---- layer_out partial over our quarter ----
        {
            const int e = t & 127, grp = t >> 7;
            const float* pp = &sc_all[qtr * 128 + grp * 16];
            const float* ob = &out_lds[grp * 16 * kE + e];
            float acc = 0.f;
            #pragma unroll
            for (int j = 0; j < 16; ++j)
                acc = fmaf(pp[j], ob[j * kE], acc);
            part8[grp][e] = acc;
        }
        __syncthreads();
        if (t < kE) {
            float s = 0.f;
            #pragma unroll
            for (int g = 0; g < 8; ++g) s += part8[g][t];
            lo_part[((size_t)b * 4 + qtr) * kE + t] = s;
        }
        group_barrier(ctr, 4 * (++barno));

        // ---- C: xb = q + sum partials; q' = xb @ w (redundant) ----
        if (t < kE) {
            const float* lp = &lo_part[(size_t)b * 4 * kE];
            xb[t] = q_s[t] + lp[t] + lp[kE + t] + lp[2 * kE + t] + lp[3 * kE + t];
        }
        __syncthreads();
        {
            const float* w = (hop == 2) ? w_out : w_int;
            const int e = t & 127, grp = t >> 7;
            float acc = 0.f;
            #pragma unroll
            for (int j = 0; j < 16; ++j) {
                const int k = grp * 16 + j;
                acc = fmaf(xb[k], w[k * kE + e], acc);
            }
            part8[grp][e] = acc;
        }
        __syncthreads();
        if (t < kE) {
            float s = 0.f;
            #pragma unroll
            for (int g = 0; g < 8; ++g) s += part8[g][t];
            q_s[t] = s;
        }
        __syncthreads();
    }

    if (qtr == 0 && t < kE) xg_t[t * kB + b] = fmaxf(q_s[t], 0.f);
}

// -------------------------------------------------------------------------
// Kernel 3: out[b,v] = sum_e relu_x[b,e] * w_final[e,v].
// 125 blocks x 256 threads, 1 column per thread. x read transposed so the
// 16 b-values per e are one uniform 64B (scalar) load.
// -------------------------------------------------------------------------
__global__ __launch_bounds__(256) void final_kernel(
    const float* __restrict__ xg_t,  // [E,B]
    const float* __restrict__ wf,    // [E,V]
    float*       __restrict__ out)   // [B,V]
{
    const int v = blockIdx.x * 256 + threadIdx.x;
    float acc[kB];
    #pragma unroll
    for (int b = 0; b < kB; ++b) acc[b] = 0.f;
    #pragma unroll 4
    for (int e = 0; e < kE; ++e) {
        const float wv = wf[(size_t)e * kV + v];
        const float* xr = xg_t + e * kB;
        #pragma unroll
        for (int b = 0; b < kB; ++b) acc[b] = fmaf(xr[b], wv, acc[b]);
    }
    #pragma unroll
    for (int b = 0; b < kB; ++b) out[(size_t)b * kV + v] = acc[b];
}

// -------------------------------------------------------------------------
extern "C" void kernel_launch(void* const* d_in, const int* in_sizes, int n_in,
                              void* d_out, int out_size, void* d_ws, size_t ws_size,
                              hipStream_t stream)
{
    const int*   queries  = (const int*)  d_in[0];
    const int*   stories  = (const int*)  d_in[1];
    const float* q_bias   = (const float*)d_in[2];
    const float* st_bias  = (const float*)d_in[3];
    const float* mem_bias = (const float*)d_in[4];
    const float* out_bias = (const float*)d_in[5];
    const float* w_int    = (const float*)d_in[6];
    const float* w_out    = (const float*)d_in[7];
    const float* w_final  = (const float*)d_in[8];
    float* out = (float*)d_out;

    // ws layout (floats): memory | output | scores_g | lo_part | xg_t | bar
    float* memory   = (float*)d_ws;
    float* output   = memory   + (size_t)kB * kM * kE;   // 1,048,576
    float* scores_g = output   + (size_t)kB * kM * kE;   // 1,048,576
    float* lo_part  = scores_g + (size_t)kB * kM;        // 8,192
    float* xg_t     = lo_part  + (size_t)kB * 4 * kE;    // 8,192
    unsigned* bar   = (unsigned*)(xg_t + (size_t)kE * kB); // 2,048

    hipMemsetAsync(bar, 0, kB * sizeof(unsigned), stream);

    embed_kernel<<<dim3(8192), dim3(256), 0, stream>>>(
        stories, st_bias, out_bias, mem_bias, memory, output);

    void* args[] = {
        (void*)&queries, (void*)&q_bias, (void*)&memory, (void*)&output,
        (void*)&w_int, (void*)&w_out, (void*)&scores_g, (void*)&lo_part,
        (void*)&xg_t, (void*)&bar
    };
    hipLaunchCooperativeKernel((const void*)hops_kernel,
                               dim3(64), dim3(1024), args, 0, stream);

    final_kernel<<<dim3(kV / 256), dim3(256), 0, stream>>>(xg_t, w_final, out);
}

// Round 4
// 202.908 us; speedup vs baseline: 1.5978x; 1.5978x over previous
//
#include <hip/hip_runtime.h>

constexpr int kB  = 16;
constexpr int kM  = 512;
constexpr int kS  = 32;
constexpr int kE  = 128;
constexpr int kV  = 32000;
constexpr int kVN = kV - 1;   // nil (zero) row index
constexpr int kMS = 132;      // padded LDS stride for mem tile

// -------------------------------------------------------------------------
// Kernel 1: story embeddings (R2-proven structure). 2 rows per 256-thread
// block, grid = 4096. 8 groups of 32 lanes; group = (row-in-pair, s-phase);
// each lane gathers float4 for 8 s values -> 16 independent loads in flight.
// enc[s][e] = 1 + (e-63)(s-15)/1024 (exact f32 match of numpy formula).
// -------------------------------------------------------------------------
__global__ __launch_bounds__(256) void embed_stories_kernel(
    const int*   __restrict__ stories,   // [B,M,S]
    const float* __restrict__ st_bias,   // [VN,E]
    const float* __restrict__ out_bias,  // [VN,E]
    const float* __restrict__ mem_bias,  // [M,E]
    float*       __restrict__ memory,    // [B,M,E]
    float*       __restrict__ output)    // [B,M,E]
{
    __shared__ int sidx[2][kS];
    __shared__ __align__(16) float pm[8][kE];
    __shared__ __align__(16) float po[8][kE];

    const int t    = threadIdx.x;
    const int row0 = blockIdx.x * 2;
    if (t < 64) sidx[t >> 5][t & 31] = stories[row0 * kS + t];
    __syncthreads();

    const int g    = t >> 5;
    const int lane = t & 31;
    const int p    = g >> 2;       // row of pair
    const int ph   = g & 3;        // s-phase
    const int e0   = lane * 4;
    const float ef0 = (float)(e0 - 63), ef1 = (float)(e0 - 62);
    const float ef2 = (float)(e0 - 61), ef3 = (float)(e0 - 60);

    float4 am = {0.f, 0.f, 0.f, 0.f};
    float4 ao = {0.f, 0.f, 0.f, 0.f};
    #pragma unroll
    for (int j = 0; j < 8; ++j) {
        const int s   = ph * 8 + j;
        const int idx = sidx[p][s];
        const float sf = (float)(s - 15) * (1.0f / 1024.0f);
        if (idx < kVN) {
            const float4 vm = *(const float4*)(st_bias  + (size_t)idx * kE + e0);
            const float4 vo = *(const float4*)(out_bias + (size_t)idx * kE + e0);
            const float c0 = fmaf(ef0, sf, 1.0f), c1 = fmaf(ef1, sf, 1.0f);
            const float c2 = fmaf(ef2, sf, 1.0f), c3 = fmaf(ef3, sf, 1.0f);
            am.x = fmaf(vm.x, c0, am.x); am.y = fmaf(vm.y, c1, am.y);
            am.z = fmaf(vm.z, c2, am.z); am.w = fmaf(vm.w, c3, am.w);
            ao.x = fmaf(vo.x, c0, ao.x); ao.y = fmaf(vo.y, c1, ao.y);
            ao.z = fmaf(vo.z, c2, ao.z); ao.w = fmaf(vo.w, c3, ao.w);
        }
    }
    *(float4*)&pm[g][e0] = am;
    *(float4*)&po[g][e0] = ao;
    __syncthreads();

    const int pr = t >> 7;
    const int e  = t & 127;
    const int row = row0 + pr;
    const int m   = row & (kM - 1);
    const float sm = pm[pr * 4 + 0][e] + pm[pr * 4 + 1][e] +
                     pm[pr * 4 + 2][e] + pm[pr * 4 + 3][e];
    const float so = po[pr * 4 + 0][e] + po[pr * 4 + 1][e] +
                     po[pr * 4 + 2][e] + po[pr * 4 + 3][e];
    memory[(size_t)row * kE + e] = sm + mem_bias[m * kE + e];
    output[(size_t)row * kE + e] = so;
}

// -------------------------------------------------------------------------
// Fence-free 4-block barrier. All cross-block data moves via agent-scope
// (sc1, coherent) RELAXED atomics, so no L2 invalidate/writeback is needed;
// __syncthreads drains each thread's coherent stores (vmcnt) before the
// RELEASE add; spin uses RELAXED coherent loads (no cache maintenance).
// -------------------------------------------------------------------------
__device__ __forceinline__ void group_barrier(unsigned* ctr, unsigned target)
{
    __syncthreads();
    if (threadIdx.x == 0) {
        __hip_atomic_fetch_add(ctr, 1u, __ATOMIC_RELEASE, __HIP_MEMORY_SCOPE_AGENT);
        while (__hip_atomic_load(ctr, __ATOMIC_RELAXED, __HIP_MEMORY_SCOPE_AGENT) < target)
            __builtin_amdgcn_s_sleep(2);
    }
    __syncthreads();
}

__device__ __forceinline__ void cstore(float* p, float v) {
    __hip_atomic_store(p, v, __ATOMIC_RELAXED, __HIP_MEMORY_SCOPE_AGENT);
}
__device__ __forceinline__ float cload(const float* p) {
    return __hip_atomic_load(p, __ATOMIC_RELAXED, __HIP_MEMORY_SCOPE_AGENT);
}

// -------------------------------------------------------------------------
// Kernel 2 (cooperative, 64 blocks x 1024 threads): q-embed + 3 hops.
// Block (b = bid>>2, qtr = bid&3) stages its quarter of memory[b]/output[b]
// into LDS once. Per hop, ONE barrier:
//   scores (own 128 rows, LDS) -> e_m = exp(s_m)  [no max: |s| = O(1)]
//   partials: numer[e] = sum_m e_m*out[m][e], denom = sum_m e_m  -> publish
//   barrier; combine redundantly: xb = q + (sum numer)/(sum denom)
//   q' = xb @ W (redundant, local)
// Partials double-buffered by hop parity. qtr==0 publishes relu(q) to xg.
// -------------------------------------------------------------------------
__global__ __launch_bounds__(1024) void hops_kernel(
    const int*   __restrict__ queries,   // [B,S]
    const float* __restrict__ q_bias,    // [VN,E]
    const float* __restrict__ memory,    // [B,M,E]
    const float* __restrict__ output,    // [B,M,E]
    const float* __restrict__ w_int,     // [E,E]
    const float* __restrict__ w_out,     // [E,E]
    float*       __restrict__ numer,     // [2,B,4,E]
    float*       __restrict__ denom,     // [2,B,4]
    float*       __restrict__ xg,        // [E,B] transposed
    unsigned*    __restrict__ bar)       // [B] counters (pre-zeroed)
{
    __shared__ __align__(16) float mem_lds[128 * kMS];  // 67584 B
    __shared__ __align__(16) float out_lds[128 * kE];   // 65536 B
    __shared__ float sc_q[128];          // exp(score) for own quarter
    __shared__ __align__(16) float q_s[kE];
    __shared__ float xb[kE];
    __shared__ __align__(16) float part8[8][kE];
    __shared__ int qidx[kS];

    const int bid = blockIdx.x;
    const int b   = bid >> 2;
    const int qtr = bid & 3;
    const int t   = threadIdx.x;
    unsigned* ctr = bar + b;

    // ---- stage quarter into LDS (coalesced float4) ----
    const float* memb = memory + ((size_t)b * kM + qtr * 128) * kE;
    const float* outb = output + ((size_t)b * kM + qtr * 128) * kE;
    #pragma unroll
    for (int i = 0; i < 4; ++i) {
        const int flat = t + i * 1024;
        const int rr = flat >> 5, ff = (flat & 31) * 4;
        *(float4*)&mem_lds[rr * kMS + ff] = *(const float4*)&memb[(size_t)rr * kE + ff];
        *(float4*)&out_lds[rr * kE  + ff] = *(const float4*)&outb[(size_t)rr * kE + ff];
    }
    if (t < kS) qidx[t] = queries[b * kS + t];
    __syncthreads();

    // ---- q embedding (threads 0..255) ----
    if (t < 256) {
        const int g = t >> 5, lane = t & 31, e0 = lane * 4;
        const float f0 = (float)(e0 - 63) * (1.0f / 1024.0f);
        const float f1 = (float)(e0 - 62) * (1.0f / 1024.0f);
        const float f2 = (float)(e0 - 61) * (1.0f / 1024.0f);
        const float f3 = (float)(e0 - 60) * (1.0f / 1024.0f);
        float4 a = {0.f, 0.f, 0.f, 0.f};
        #pragma unroll
        for (int j = 0; j < 4; ++j) {
            const int s   = g * 4 + j;
            const int idx = qidx[s];
            const float sf = (float)(s - 15);
            if (idx < kVN) {
                const float4 v = *(const float4*)&q_bias[(size_t)idx * kE + e0];
                a.x = fmaf(v.x, fmaf(f0, sf, 1.f), a.x);
                a.y = fmaf(v.y, fmaf(f1, sf, 1.f), a.y);
                a.z = fmaf(v.z, fmaf(f2, sf, 1.f), a.z);
                a.w = fmaf(v.w, fmaf(f3, sf, 1.f), a.w);
            }
        }
        *(float4*)&part8[g][e0] = a;
    }
    __syncthreads();
    if (t < kE) {
        float s = 0.f;
        #pragma unroll
        for (int g = 0; g < 8; ++g) s += part8[g][t];
        q_s[t] = s;
    }
    __syncthreads();

    const int grp = t >> 7;     // 0..7
    const int e   = t & 127;

    for (int hop = 0; hop < 3; ++hop) {
        // ---- scores for own 128 rows: 8 lanes x 16 e per row ----
        {
            const int rw = t >> 3, sub = t & 7;
            const float4* qv = (const float4*)&q_s[sub * 16];
            const float4* mv = (const float4*)&mem_lds[rw * kMS + sub * 16];
            float d = 0.f;
            #pragma unroll
            for (int i = 0; i < 4; ++i) {
                const float4 m4 = mv[i], q4 = qv[i];
                d = fmaf(m4.x, q4.x, d); d = fmaf(m4.y, q4.y, d);
                d = fmaf(m4.z, q4.z, d); d = fmaf(m4.w, q4.w, d);
            }
            d += __shfl_down(d, 4);
            d += __shfl_down(d, 2);
            d += __shfl_down(d, 1);
            if (sub == 0) sc_q[rw] = __expf(d);   // no max-sub: |s| = O(1)
        }
        __syncthreads();

        // ---- numer partial: numer[e] = sum_{m in qtr} e_m * out[m][e] ----
        {
            float acc = 0.f;
            const float* pp = &sc_q[grp * 16];
            const float* ob = &out_lds[grp * 16 * kE + e];
            #pragma unroll
            for (int j = 0; j < 16; ++j)
                acc = fmaf(pp[j], ob[j * kE], acc);
            part8[grp][e] = acc;
        }
        __syncthreads();

        const int pb = hop & 1;
        float* nq = numer + (((size_t)pb * kB + b) * 4 + qtr) * kE;
        if (t < kE) {
            float s = 0.f;
            #pragma unroll
            for (int g = 0; g < 8; ++g) s += part8[g][t];
            cstore(&nq[t], s);
        } else if (t < 192) {
            // denom partial: one wave reduces sc_q[0..127]
            const int l = t - 128;
            float s2 = sc_q[l] + sc_q[l + 64];
            #pragma unroll
            for (int off = 32; off; off >>= 1) s2 += __shfl_down(s2, off);
            if (l == 0) cstore(&denom[((size_t)pb * kB + b) * 4 + qtr], s2);
        }

        group_barrier(ctr, 4u * (hop + 1));

        // ---- combine redundantly: xb = q + sum(numer)/sum(denom) ----
        if (t < kE) {
            const float* nn = numer + ((size_t)pb * kB + b) * 4 * kE;
            const float* dd = denom + ((size_t)pb * kB + b) * 4;
            const float ns = cload(&nn[t]) + cload(&nn[kE + t]) +
                             cload(&nn[2 * kE + t]) + cload(&nn[3 * kE + t]);
            const float ds = cload(&dd[0]) + cload(&dd[1]) +
                             cload(&dd[2]) + cload(&dd[3]);
            xb[t] = q_s[t] + ns / ds;
        }
        __syncthreads();

        // ---- q' = xb @ W (redundant, 8 k-groups of 16) ----
        {
            const float* w = (hop == 2) ? w_out : w_int;
            float acc = 0.f;
            #pragma unroll
            for (int j = 0; j < 16; ++j) {
                const int k = grp * 16 + j;
                acc = fmaf(xb[k], w[k * kE + e], acc);
            }
            part8[grp][e] = acc;
        }
        __syncthreads();
        if (t < kE) {
            float s = 0.f;
            #pragma unroll
            for (int g = 0; g < 8; ++g) s += part8[g][t];
            q_s[t] = s;
        }
        __syncthreads();
    }

    if (qtr == 0 && t < kE) xg[t * kB + b] = fmaxf(q_s[t], 0.f);
}

// -------------------------------------------------------------------------
// Kernel 3: out[b,v] = sum_e relu_x[b,e] * w_final[e,v].
// 250 blocks x 256 threads: v = bid*128 + (t&127), e-half = t>>7.
// xg read transposed -> uniform 64B scalar loads per e. Halves combined
// through LDS; halved serial wf-load chain + 250 CUs of coverage.
// -------------------------------------------------------------------------
__global__ __launch_bounds__(256) void final_kernel(
    const float* __restrict__ xg,   // [E,B]
    const float* __restrict__ wf,   // [E,V]
    float*       __restrict__ out)  // [B,V]
{
    __shared__ float ps[128 * kB];
    const int t = threadIdx.x;
    const int v = blockIdx.x * 128 + (t & 127);
    const int h = t >> 7;

    float acc[kB];
    #pragma unroll
    for (int b = 0; b < kB; ++b) acc[b] = 0.f;

    const int e0 = h * 64;
    #pragma unroll 4
    for (int ei = 0; ei < 64; ++ei) {
        const int e = e0 + ei;
        const float wv = wf[(size_t)e * kV + v];
        const float* xr = xg + e * kB;       // uniform -> scalar loads
        #pragma unroll
        for (int b = 0; b < kB; ++b) acc[b] = fmaf(xr[b], wv, acc[b]);
    }

    if (h == 1) {
        #pragma unroll
        for (int b = 0; b < kB; ++b) ps[(t & 127) * kB + b] = acc[b];
    }
    __syncthreads();
    if (h == 0) {
        #pragma unroll
        for (int b = 0; b < kB; ++b)
            out[(size_t)b * kV + v] = acc[b] + ps[(t & 127) * kB + b];
    }
}

// -------------------------------------------------------------------------
extern "C" void kernel_launch(void* const* d_in, const int* in_sizes, int n_in,
                              void* d_out, int out_size, void* d_ws, size_t ws_size,
                              hipStream_t stream)
{
    const int*   queries  = (const int*)  d_in[0];
    const int*   stories  = (const int*)  d_in[1];
    const float* q_bias   = (const float*)d_in[2];
    const float* st_bias  = (const float*)d_in[3];
    const float* mem_bias = (const float*)d_in[4];
    const float* out_bias = (const float*)d_in[5];
    const float* w_int    = (const float*)d_in[6];
    const float* w_out    = (const float*)d_in[7];
    const float* w_final  = (const float*)d_in[8];
    float* out = (float*)d_out;

    // ws layout (floats): memory | output | numer | denom | xg | bar
    float* memory = (float*)d_ws;
    float* output = memory + (size_t)kB * kM * kE;        // 1,048,576
    float* numer  = output + (size_t)kB * kM * kE;        // 1,048,576
    float* denom  = numer  + 2 * kB * 4 * kE;             // 16,384
    float* xg     = denom  + 2 * kB * 4;                  // 128
    unsigned* bar = (unsigned*)(xg + kE * kB);            // 2,048

    hipMemsetAsync(bar, 0, kB * sizeof(unsigned), stream);

    embed_stories_kernel<<<dim3((kB * kM) / 2), dim3(256), 0, stream>>>(
        stories, st_bias, out_bias, mem_bias, memory, output);

    void* args[] = {
        (void*)&queries, (void*)&q_bias, (void*)&memory, (void*)&output,
        (void*)&w_int, (void*)&w_out, (void*)&numer, (void*)&denom,
        (void*)&xg, (void*)&bar
    };
    hipLaunchCooperativeKernel((const void*)hops_kernel,
                               dim3(64), dim3(1024), args, 0, stream);

    final_kernel<<<dim3(kV / 128), dim3(256), 0, stream>>>(xg, w_final, out);
}